// Round 14
// baseline (107.935 us; speedup 1.0000x reference)
//
#include <hip/hip_runtime.h>
#include <cstdint>
#include <cstddef>

// x[64][1024][32] f32, W[1024][32] f32, b[1024] f32 -> out[64][1024][1024] f32
#define BATCH   64
#define SEQLEN  1024
#define KDIM    32
#define ODIM    1024
#define NTOK    (BATCH * SEQLEN)

#define NWP 8        // wpartial blocks
#define NQX 1024     // quant_x blocks (65536*32 / 8 elems-per-thread / 256)

typedef __attribute__((ext_vector_type(8))) short bf16x8;   // 8 bf16 = 4 VGPRs
typedef __attribute__((ext_vector_type(4))) float f32x4;

// exact f32 -> bf16 truncation; exact for integer-valued f32 |v| <= 255 and {-1,0,1}
__device__ __forceinline__ unsigned short f32_to_bf16_exact(float f) {
    union { float f; unsigned int u; } cv; cv.f = f;
    return (unsigned short)(cv.u >> 16);
}

// ---------------------------------------------------------------------------
// Kernel 1: merged prep — two independent jobs dispatched by block range.
//   blocks [0,8):        W |.| partial sums (deterministic tree reduce)
//   blocks [8, 8+1024):  activation quant x8-vectorized -> xq int bf16,
//                        rxs = clip(absmax,1e-5)/127
// ---------------------------------------------------------------------------
__global__ __launch_bounds__(256) void prep_kernel(const float* __restrict__ x,
                                                   const float* __restrict__ W,
                                                   float* __restrict__ partial,
                                                   unsigned short* __restrict__ xq,
                                                   float* __restrict__ rxs) {
    const int blk = blockIdx.x;
    const int t   = threadIdx.x;

    if (blk < NWP) {
        // ---- W |.| partial sums: 8 blocks x 256 threads x 16 elems ----
        __shared__ float red[256];
        const float4* W4 = reinterpret_cast<const float4*>(W) + (size_t)blk * 1024 + t * 4;
        float acc = 0.f;
        #pragma unroll
        for (int j = 0; j < 4; ++j) {
            float4 v = W4[j];
            acc += fabsf(v.x) + fabsf(v.y) + fabsf(v.z) + fabsf(v.w);
        }
        red[t] = acc;
        __syncthreads();
        for (int step = 128; step > 0; step >>= 1) {
            if (t < step) red[t] += red[t + step];
            __syncthreads();
        }
        if (t == 0) partial[blk] = red[0];
    } else {
        // ---- activation quant: thread owns 8 elems; 4 threads = 1 token ----
        const int g = (blk - NWP) * 256 + t;         // 8-elem group index
        const float* xg = x + ((size_t)g << 3);
        float4 xa = *reinterpret_cast<const float4*>(xg);
        float4 xb = *reinterpret_cast<const float4*>(xg + 4);
        float a = fmaxf(fmaxf(fmaxf(fabsf(xa.x), fabsf(xa.y)),
                              fmaxf(fabsf(xa.z), fabsf(xa.w))),
                        fmaxf(fmaxf(fabsf(xb.x), fabsf(xb.y)),
                              fmaxf(fabsf(xb.z), fabsf(xb.w))));
        a = fmaxf(a, __shfl_xor(a, 1, 4));           // 4-lane token group
        a = fmaxf(a, __shfl_xor(a, 2, 4));
        const float am = fmaxf(a, 1e-5f);
        const float scale = 127.0f / am;             // |v*scale|<=127: clip can't bind
        float e[8] = {xa.x, xa.y, xa.z, xa.w, xb.x, xb.y, xb.z, xb.w};
        union { bf16x8 v; unsigned short s[8]; } u;
        #pragma unroll
        for (int j = 0; j < 8; ++j)
            u.s[j] = f32_to_bf16_exact(rintf(e[j] * scale));   // int, exact bf16
        *reinterpret_cast<bf16x8*>(xq + ((size_t)g << 3)) = u.v;
        if ((g & 3) == 0) rxs[g >> 2] = am * (1.0f / 127.0f);
    }
}

// ---------------------------------------------------------------------------
// Kernel 2: BitLinear GEMM — round-12 structure + NON-TEMPORAL stores.
// Tile 16 s x 256 o x 32 b; 512 threads / 8 waves; wave wid -> o-quarter
// (wid&3)*64, b-octet. Grid 512 = 8 XCD x 64; swizzle as r12 (XCD-disjoint
// xq slices; row co-assembly within one XCD). Single change vs r12:
// __builtin_nontemporal_store on the output (write-once data; 64 B-complete
// chunks match HBM3E granule; frees L2 from 268 MB of dirty write-back).
// ---------------------------------------------------------------------------
__global__ __launch_bounds__(512) void bitgemm(
    const unsigned short* __restrict__ xq,       // [65536][32] bf16 int
    const float*          __restrict__ rxs,      // [65536] am/127
    const float*          __restrict__ W,        // [1024][32] f32
    const float*          __restrict__ partial,  // [8]
    const float*          __restrict__ bias,     // [1024]
    float* __restrict__ out)                     // [65536][1024]
{
    const int lane = threadIdx.x & 63;
    const int wid  = threadIdx.x >> 6;        // 0..7
    const int l15  = lane & 15;
    const int hi   = lane >> 4;               // 0..3

    // XCD-aware swizzle (bijective: 512 = 8 XCDs x 64)
    const int lb    = (blockIdx.x & 7) * 64 + (blockIdx.x >> 3);
    const int sblk  = lb >> 3;                // 64 s-chunks (8 per XCD)
    const int oblk  = lb & 3;                 // 4 o-blocks of 256
    const int bhalf = (lb >> 2) & 1;          // 2 b-halves of 32
    const int o0    = oblk * 256 + (wid & 3) * 64;   // wave's o-base
    const int s0    = sblk * 16;
    const int bq    = bhalf * 2 + (wid >> 2); // wave's b-octet 0..3 (16 b each)

    // ---- weight scale from partials (uniform scalar path) ----
    float tot = 0.f;
    #pragma unroll
    for (int p = 0; p < 8; ++p) tot += partial[p];
    const float rw = fmaxf(tot * (1.0f / 32768.0f), 1e-5f);   // 1/scale_w
    const float sc = 1.0f / rw;                               // scale_w

    // ---- A fragments: inline ternary quant of W (once per wave) ----
    bf16x8 afrag[4];
    #pragma unroll
    for (int f = 0; f < 4; ++f) {
        const float* wr = W + (size_t)(o0 + f * 16 + l15) * KDIM + hi * 8;
        float4 wa = *reinterpret_cast<const float4*>(wr);
        float4 wb = *reinterpret_cast<const float4*>(wr + 4);
        float e[8] = {wa.x, wa.y, wa.z, wa.w, wb.x, wb.y, wb.z, wb.w};
        union { bf16x8 v; unsigned short s[8]; } u;
        #pragma unroll
        for (int j = 0; j < 8; ++j)
            u.s[j] = f32_to_bf16_exact(fminf(fmaxf(rintf(e[j] * sc), -1.0f), 1.0f));
        afrag[f] = u.v;
    }

    // ---- bias + positional encoding in-register (once per block) ----
    const float C  = -0.012976281620653759f;  // -log2(10000)/1024
    const float sf = (float)(s0 + l15);
    f32x4 addf[4];
    #pragma unroll
    for (int f = 0; f < 4; ++f) {
        const int oe = o0 + f * 16 + hi * 4;              // multiple of 4
        f32x4 bv = *reinterpret_cast<const f32x4*>(bias + oe);
        float a0 = sf * exp2f(C * (float)oe);
        float a1 = sf * exp2f(C * (float)(oe + 2));
        addf[f][0] = bv[0] + sinf(a0);
        addf[f][1] = bv[1] + cosf(a0);
        addf[f][2] = bv[2] + sinf(a1);
        addf[f][3] = bv[3] + cosf(a1);
    }

    // ---- b-loop: 16 iterations, 2x unrolled (8 stores / 2 loads in flight) ----
    #pragma unroll 2
    for (int i = 0; i < 16; ++i) {
        const int b   = bq * 16 + i;
        const int tok = (b << 10) + s0 + l15;

        bf16x8 bfrag = *reinterpret_cast<const bf16x8*>(
            xq + ((size_t)tok << 5) + hi * 8);
        const float rxw = rxs[tok] * rw;

        float* op = out + ((size_t)tok << 10) + o0 + hi * 4;
        #pragma unroll
        for (int f = 0; f < 4; ++f) {
            f32x4 acc = (f32x4){0.f, 0.f, 0.f, 0.f};
            acc = __builtin_amdgcn_mfma_f32_16x16x32_bf16(afrag[f], bfrag, acc, 0, 0, 0);
            f32x4 r;
            #pragma unroll
            for (int j = 0; j < 4; ++j)
                r[j] = fmaf(acc[j], rxw, addf[f][j]);
            __builtin_nontemporal_store(r, reinterpret_cast<f32x4*>(op + f * 16));
        }
    }
}

// ---------------------------------------------------------------------------
extern "C" void kernel_launch(void* const* d_in, const int* in_sizes, int n_in,
                              void* d_out, int out_size, void* d_ws, size_t ws_size,
                              hipStream_t stream) {
    const float* x = (const float*)d_in[0];   // [64][1024][32]
    const float* W = (const float*)d_in[1];   // [1024][32]
    const float* b = (const float*)d_in[2];   // [1024]
    float* out = (float*)d_out;

    // ws: partial f32[8] @0 | rxs f32[65536] @256B | xq bf16[65536][32] @512KB
    char* wsb = (char*)d_ws;
    float*          partial = (float*)wsb;
    float*          rxs     = (float*)(wsb + 256);
    unsigned short* xq      = (unsigned short*)(wsb + (512u << 10));

    prep_kernel<<<NWP + NQX, 256, 0, stream>>>(x, W, partial, xq, rxs);
    bitgemm<<<512, 512, 0, stream>>>(xq, rxs, W, partial, b, out);
}

// Round 15
// 58.087 us; speedup vs baseline: 1.8582x; 1.8582x over previous
//
#include <hip/hip_runtime.h>
#include <cstdint>
#include <cstddef>

// x[64][1024][32] f32, W[1024][32] f32, b[1024] f32 -> out[64][1024][1024] f32
#define BATCH   64
#define SEQLEN  1024
#define KDIM    32
#define ODIM    1024
#define NTOK    (BATCH * SEQLEN)

#define NWP 8        // wpartial blocks
#define NQX 1024     // quant_x blocks (65536*32 / 8 elems-per-thread / 256)

typedef __attribute__((ext_vector_type(8))) short bf16x8;   // 8 bf16 = 4 VGPRs
typedef __attribute__((ext_vector_type(4))) float f32x4;

// exact f32 -> bf16 truncation; exact for integer-valued f32 |v| <= 255 and {-1,0,1}
__device__ __forceinline__ unsigned short f32_to_bf16_exact(float f) {
    union { float f; unsigned int u; } cv; cv.f = f;
    return (unsigned short)(cv.u >> 16);
}

// ---------------------------------------------------------------------------
// Kernel 1: merged prep — two independent jobs dispatched by block range.
//   blocks [0,8):        W |.| partial sums (deterministic tree reduce)
//   blocks [8, 8+1024):  activation quant x8-vectorized -> xq int bf16,
//                        rxs = clip(absmax,1e-5)/127
// ---------------------------------------------------------------------------
__global__ __launch_bounds__(256) void prep_kernel(const float* __restrict__ x,
                                                   const float* __restrict__ W,
                                                   float* __restrict__ partial,
                                                   unsigned short* __restrict__ xq,
                                                   float* __restrict__ rxs) {
    const int blk = blockIdx.x;
    const int t   = threadIdx.x;

    if (blk < NWP) {
        // ---- W |.| partial sums: 8 blocks x 256 threads x 16 elems ----
        __shared__ float red[256];
        const float4* W4 = reinterpret_cast<const float4*>(W) + (size_t)blk * 1024 + t * 4;
        float acc = 0.f;
        #pragma unroll
        for (int j = 0; j < 4; ++j) {
            float4 v = W4[j];
            acc += fabsf(v.x) + fabsf(v.y) + fabsf(v.z) + fabsf(v.w);
        }
        red[t] = acc;
        __syncthreads();
        for (int step = 128; step > 0; step >>= 1) {
            if (t < step) red[t] += red[t + step];
            __syncthreads();
        }
        if (t == 0) partial[blk] = red[0];
    } else {
        // ---- activation quant: thread owns 8 elems; 4 threads = 1 token ----
        const int g = (blk - NWP) * 256 + t;         // 8-elem group index
        const float* xg = x + ((size_t)g << 3);
        float4 xa = *reinterpret_cast<const float4*>(xg);
        float4 xb = *reinterpret_cast<const float4*>(xg + 4);
        float a = fmaxf(fmaxf(fmaxf(fabsf(xa.x), fabsf(xa.y)),
                              fmaxf(fabsf(xa.z), fabsf(xa.w))),
                        fmaxf(fmaxf(fabsf(xb.x), fabsf(xb.y)),
                              fmaxf(fabsf(xb.z), fabsf(xb.w))));
        a = fmaxf(a, __shfl_xor(a, 1, 4));           // 4-lane token group
        a = fmaxf(a, __shfl_xor(a, 2, 4));
        const float am = fmaxf(a, 1e-5f);
        const float scale = 127.0f / am;             // |v*scale|<=127: clip can't bind
        float e[8] = {xa.x, xa.y, xa.z, xa.w, xb.x, xb.y, xb.z, xb.w};
        union { bf16x8 v; unsigned short s[8]; } u;
        #pragma unroll
        for (int j = 0; j < 8; ++j)
            u.s[j] = f32_to_bf16_exact(rintf(e[j] * scale));   // int, exact bf16
        *reinterpret_cast<bf16x8*>(xq + ((size_t)g << 3)) = u.v;
        if ((g & 3) == 0) rxs[g >> 2] = am * (1.0f / 127.0f);
    }
}

// ---------------------------------------------------------------------------
// Kernel 2: BitLinear GEMM — round-12 structure (verified best: 56.5 µs).
// Tile 16 s x 256 o x 32 b; 512 threads / 8 waves; wave wid -> o-quarter
// (wid&3)*64, b-octet (wid>>2). Grid 512 = 8 XCD x 64; swizzle
// lb=(phys&7)*64+(phys>>3): XCD k owns s-chunks [8k,8k+8) -> disjoint xq
// slice; the 4 blocks co-assembling an output row share (s-chunk,bhalf) ->
// same XCD's L2. Plain f32x4 stores THROUGH L2 (nt measured -51 µs, r14).
// Occupancy 2 blocks/CU x 8 waves = 16 waves/CU.
// ---------------------------------------------------------------------------
__global__ __launch_bounds__(512) void bitgemm(
    const unsigned short* __restrict__ xq,       // [65536][32] bf16 int
    const float*          __restrict__ rxs,      // [65536] am/127
    const float*          __restrict__ W,        // [1024][32] f32
    const float*          __restrict__ partial,  // [8]
    const float*          __restrict__ bias,     // [1024]
    float* __restrict__ out)                     // [65536][1024]
{
    const int lane = threadIdx.x & 63;
    const int wid  = threadIdx.x >> 6;        // 0..7
    const int l15  = lane & 15;
    const int hi   = lane >> 4;               // 0..3

    // XCD-aware swizzle (bijective: 512 = 8 XCDs x 64)
    const int lb    = (blockIdx.x & 7) * 64 + (blockIdx.x >> 3);
    const int sblk  = lb >> 3;                // 64 s-chunks (8 per XCD)
    const int oblk  = lb & 3;                 // 4 o-blocks of 256
    const int bhalf = (lb >> 2) & 1;          // 2 b-halves of 32
    const int o0    = oblk * 256 + (wid & 3) * 64;   // wave's o-base
    const int s0    = sblk * 16;
    const int bq    = bhalf * 2 + (wid >> 2); // wave's b-octet 0..3 (16 b each)

    // ---- weight scale from partials (uniform scalar path) ----
    float tot = 0.f;
    #pragma unroll
    for (int p = 0; p < 8; ++p) tot += partial[p];
    const float rw = fmaxf(tot * (1.0f / 32768.0f), 1e-5f);   // 1/scale_w
    const float sc = 1.0f / rw;                               // scale_w

    // ---- A fragments: inline ternary quant of W (once per wave) ----
    bf16x8 afrag[4];
    #pragma unroll
    for (int f = 0; f < 4; ++f) {
        const float* wr = W + (size_t)(o0 + f * 16 + l15) * KDIM + hi * 8;
        float4 wa = *reinterpret_cast<const float4*>(wr);
        float4 wb = *reinterpret_cast<const float4*>(wr + 4);
        float e[8] = {wa.x, wa.y, wa.z, wa.w, wb.x, wb.y, wb.z, wb.w};
        union { bf16x8 v; unsigned short s[8]; } u;
        #pragma unroll
        for (int j = 0; j < 8; ++j)
            u.s[j] = f32_to_bf16_exact(fminf(fmaxf(rintf(e[j] * sc), -1.0f), 1.0f));
        afrag[f] = u.v;
    }

    // ---- bias + positional encoding in-register (once per block) ----
    const float C  = -0.012976281620653759f;  // -log2(10000)/1024
    const float sf = (float)(s0 + l15);
    f32x4 addf[4];
    #pragma unroll
    for (int f = 0; f < 4; ++f) {
        const int oe = o0 + f * 16 + hi * 4;              // multiple of 4
        f32x4 bv = *reinterpret_cast<const f32x4*>(bias + oe);
        float a0 = sf * exp2f(C * (float)oe);
        float a1 = sf * exp2f(C * (float)(oe + 2));
        addf[f][0] = bv[0] + sinf(a0);
        addf[f][1] = bv[1] + cosf(a0);
        addf[f][2] = bv[2] + sinf(a1);
        addf[f][3] = bv[3] + cosf(a1);
    }

    // ---- b-loop: 16 iterations, 2x unrolled (8 stores / 2 loads in flight) ----
    #pragma unroll 2
    for (int i = 0; i < 16; ++i) {
        const int b   = bq * 16 + i;
        const int tok = (b << 10) + s0 + l15;

        bf16x8 bfrag = *reinterpret_cast<const bf16x8*>(
            xq + ((size_t)tok << 5) + hi * 8);
        const float rxw = rxs[tok] * rw;

        float* op = out + ((size_t)tok << 10) + o0 + hi * 4;
        #pragma unroll
        for (int f = 0; f < 4; ++f) {
            f32x4 acc = (f32x4){0.f, 0.f, 0.f, 0.f};
            acc = __builtin_amdgcn_mfma_f32_16x16x32_bf16(afrag[f], bfrag, acc, 0, 0, 0);
            f32x4 r;
            #pragma unroll
            for (int j = 0; j < 4; ++j)
                r[j] = fmaf(acc[j], rxw, addf[f][j]);
            *reinterpret_cast<f32x4*>(op + f * 16) = r;
        }
    }
}

// ---------------------------------------------------------------------------
extern "C" void kernel_launch(void* const* d_in, const int* in_sizes, int n_in,
                              void* d_out, int out_size, void* d_ws, size_t ws_size,
                              hipStream_t stream) {
    const float* x = (const float*)d_in[0];   // [64][1024][32]
    const float* W = (const float*)d_in[1];   // [1024][32]
    const float* b = (const float*)d_in[2];   // [1024]
    float* out = (float*)d_out;

    // ws: partial f32[8] @0 | rxs f32[65536] @256B | xq bf16[65536][32] @512KB
    char* wsb = (char*)d_ws;
    float*          partial = (float*)wsb;
    float*          rxs     = (float*)(wsb + 256);
    unsigned short* xq      = (unsigned short*)(wsb + (512u << 10));

    prep_kernel<<<NWP + NQX, 256, 0, stream>>>(x, W, partial, xq, rxs);
    bitgemm<<<512, 512, 0, stream>>>(xq, rxs, W, partial, b, out);
}